// Round 1
// baseline (1127.016 us; speedup 1.0000x reference)
//
#include <hip/hip_runtime.h>

// Problem constants (fixed by setup_inputs).
#define NQTOT   256       // queries
#define DDIM    128       // feature dim
#define NKEYS   200000    // stored keys
#define SDIM    256       // slot dim
#define TOPK    8

// Phase A tiling.
#define NCHUNK  125
#define CHUNK   1600            // NCHUNK*CHUNK == NKEYS
#define TILEK   32              // keys staged per LDS tile
#define NTILES  (CHUNK/TILEK)   // 50
#define BQ      64              // queries per block
#define QGROUPS (NQTOT/BQ)      // 4

#define D4      (DDIM/4)        // 32 float4 per row
#define QROW    (D4+1)          // padded row (float4 units)
#define QS_F4   (BQ*QROW)       // 2112
#define KS_F4   (TILEK*QROW)    // 1056
#define SMEM_A  ((QS_F4+KS_F4)*16)   // 50688 B

static_assert(NCHUNK * CHUNK == NKEYS, "chunking must cover keys exactly");

#define NEG_INF (-3.402823466e+38f)

// Min-replace top-8 insert; all indices constant after unroll (no scratch).
__device__ __forceinline__ void topk_insert(float (&vs)[TOPK], int (&vi)[TOPK],
                                            float &vmin, float s, int idx) {
    if (s <= vmin) return;
    bool done = false;
#pragma unroll
    for (int j = 0; j < TOPK; ++j) {
        if (!done && vs[j] == vmin) { vs[j] = s; vi[j] = idx; done = true; }
    }
    float m = vs[0];
#pragma unroll
    for (int j = 1; j < TOPK; ++j) m = fminf(m, vs[j]);
    vmin = m;
}

// ---------------- Phase A: chunked fp32 scoring + per-chunk top-8 ----------------
__global__ __launch_bounds__(256, 2)
void score_chunk_topk(const float* __restrict__ query,
                      const float* __restrict__ keys,
                      float* __restrict__ ws_s,
                      int*   __restrict__ ws_i) {
    const int chunk = blockIdx.x;     // 0..124
    const int qgrp  = blockIdx.y;     // 0..3
    const int tid   = threadIdx.x;    // 0..255
    const int qg    = tid & 15;       // query group (16)
    const int kg    = tid >> 4;       // key group   (16)

    extern __shared__ char smem[];
    float4* qs4 = (float4*)smem;                      // [BQ][QROW]
    float4* ks4 = (float4*)(smem + QS_F4 * 16);       // [TILEK][QROW]

    // Stage 64 queries (coalesced float4).
    const float4* qg4 = (const float4*)query;
    for (int f = tid; f < BQ * D4; f += 256) {
        int q = f >> 5, d4 = f & 31;
        qs4[q * QROW + d4] = qg4[(qgrp * BQ + q) * D4 + d4];
    }

    // Per-thread top-8 for 4 queries (q_loc = qg + 16*iq).
    float vs[4][TOPK]; int vi[4][TOPK]; float vmin[4];
#pragma unroll
    for (int iq = 0; iq < 4; ++iq) {
        vmin[iq] = NEG_INF;
#pragma unroll
        for (int j = 0; j < TOPK; ++j) { vs[iq][j] = NEG_INF; vi[iq][j] = -1; }
    }

    const int key0 = chunk * CHUNK;
    const float4* k4g = (const float4*)keys;

    for (int tile = 0; tile < NTILES; ++tile) {
        const int kbase = key0 + tile * TILEK;
        __syncthreads();   // queries staged (iter 0) / prev tile compute done
        for (int f = tid; f < TILEK * D4; f += 256) {
            int kt = f >> 5, d4 = f & 31;
            ks4[kt * QROW + d4] = k4g[(size_t)(kbase + kt) * D4 + d4];
        }
        __syncthreads();

        float acc[4][2];
#pragma unroll
        for (int iq = 0; iq < 4; ++iq)
#pragma unroll
            for (int ik = 0; ik < 2; ++ik) acc[iq][ik] = 0.0f;

#pragma unroll 4
        for (int d4 = 0; d4 < D4; ++d4) {
            float4 qv[4], kv[2];
#pragma unroll
            for (int iq = 0; iq < 4; ++iq) qv[iq] = qs4[(qg + 16 * iq) * QROW + d4];
#pragma unroll
            for (int ik = 0; ik < 2; ++ik) kv[ik] = ks4[(kg + 16 * ik) * QROW + d4];
#pragma unroll
            for (int iq = 0; iq < 4; ++iq)
#pragma unroll
                for (int ik = 0; ik < 2; ++ik) {
                    acc[iq][ik] = fmaf(qv[iq].x, kv[ik].x, acc[iq][ik]);
                    acc[iq][ik] = fmaf(qv[iq].y, kv[ik].y, acc[iq][ik]);
                    acc[iq][ik] = fmaf(qv[iq].z, kv[ik].z, acc[iq][ik]);
                    acc[iq][ik] = fmaf(qv[iq].w, kv[ik].w, acc[iq][ik]);
                }
        }

#pragma unroll
        for (int iq = 0; iq < 4; ++iq)
#pragma unroll
            for (int ik = 0; ik < 2; ++ik)
                topk_insert(vs[iq], vi[iq], vmin[iq], acc[iq][ik],
                            kbase + kg + 16 * ik);
    }

    // Block-level merge: for each iq, dump all 256 lists; kg==0 threads merge
    // the 16 lists belonging to their query and write per-(query,chunk) top-8.
    float* dump_s = (float*)smem;                 // [256][TOPK]
    int*   dump_i = (int*)(smem + 256 * TOPK * 4);
    for (int iq = 0; iq < 4; ++iq) {
        __syncthreads();
#pragma unroll
        for (int j = 0; j < TOPK; ++j) {
            dump_s[tid * TOPK + j] = vs[iq][j];
            dump_i[tid * TOPK + j] = vi[iq][j];
        }
        __syncthreads();
        if (kg == 0) {
            float ms[TOPK]; int mi[TOPK]; float mmin = vmin[iq];
#pragma unroll
            for (int j = 0; j < TOPK; ++j) { ms[j] = vs[iq][j]; mi[j] = vi[iq][j]; }
            for (int kk = 1; kk < 16; ++kk) {
                int src = qg + 16 * kk;
                for (int j = 0; j < TOPK; ++j)
                    topk_insert(ms, mi, mmin, dump_s[src * TOPK + j],
                                dump_i[src * TOPK + j]);
            }
            const int q = qgrp * BQ + qg + 16 * iq;
            const int base = (q * NCHUNK + chunk) * TOPK;
#pragma unroll
            for (int j = 0; j < TOPK; ++j) { ws_s[base + j] = ms[j]; ws_i[base + j] = mi[j]; }
        }
    }
}

// ---------------- Phase B: global merge + sort + slot gather ----------------
__global__ __launch_bounds__(256)
void topk_merge_gather(const float* __restrict__ ws_s,
                       const int*   __restrict__ ws_i,
                       const float* __restrict__ slots,
                       float* __restrict__ out) {
    const int q = blockIdx.x;
    const int t = threadIdx.x;

    __shared__ float ds[256 * TOPK];
    __shared__ int   di[256 * TOPK];
    __shared__ float fin_s[TOPK];
    __shared__ int   fin_i[TOPK];

    float vs[TOPK]; int vi[TOPK]; float vmin = NEG_INF;
#pragma unroll
    for (int j = 0; j < TOPK; ++j) { vs[j] = NEG_INF; vi[j] = -1; }

    const int ncand = NCHUNK * TOPK;  // 1000
    for (int c = t; c < ncand; c += 256)
        topk_insert(vs, vi, vmin, ws_s[q * ncand + c], ws_i[q * ncand + c]);

#pragma unroll
    for (int j = 0; j < TOPK; ++j) { ds[t * TOPK + j] = vs[j]; di[t * TOPK + j] = vi[j]; }
    __syncthreads();

    for (int step = 128; step >= 1; step >>= 1) {
        if (t < step) {
            for (int j = 0; j < TOPK; ++j)
                topk_insert(vs, vi, vmin, ds[(t + step) * TOPK + j],
                            di[(t + step) * TOPK + j]);
#pragma unroll
            for (int j = 0; j < TOPK; ++j) { ds[t * TOPK + j] = vs[j]; di[t * TOPK + j] = vi[j]; }
        }
        __syncthreads();
    }

    if (t == 0) {
        // Sort descending, tie-break lower index (matches lax.top_k).
#pragma unroll
        for (int i = 0; i < TOPK; ++i)
#pragma unroll
            for (int j = 0; j < TOPK - 1 - i; ++j) {
                bool swp = (vs[j + 1] > vs[j]) ||
                           (vs[j + 1] == vs[j] && vi[j + 1] < vi[j]);
                if (swp) {
                    float tf = vs[j]; vs[j] = vs[j + 1]; vs[j + 1] = tf;
                    int   ti = vi[j]; vi[j] = vi[j + 1]; vi[j + 1] = ti;
                }
            }
#pragma unroll
        for (int j = 0; j < TOPK; ++j) { fin_s[j] = vs[j]; fin_i[j] = vi[j]; }
    }
    __syncthreads();

    // Gather slots: out layout [256][8][256] then scores [256][8].
    const float4* slots4 = (const float4*)slots;
    float4* out4 = (float4*)out;
    const int s4row = SDIM / 4;                 // 64 float4 per slot row
    for (int f = t; f < TOPK * s4row; f += 256) {
        int j = f >> 6, s4 = f & 63;
        out4[(size_t)q * (TOPK * s4row) + f] =
            slots4[(size_t)fin_i[j] * s4row + s4];
    }
    if (t < TOPK)
        out[(size_t)NQTOT * TOPK * SDIM + q * TOPK + t] = fin_s[t];
}

extern "C" void kernel_launch(void* const* d_in, const int* in_sizes, int n_in,
                              void* d_out, int out_size, void* d_ws, size_t ws_size,
                              hipStream_t stream) {
    const float* query = (const float*)d_in[0];
    const float* keys  = (const float*)d_in[1];
    const float* slots = (const float*)d_in[2];
    (void)in_sizes; (void)n_in; (void)out_size; (void)ws_size;

    float* ws_s = (float*)d_ws;
    int*   ws_i = (int*)((char*)d_ws + (size_t)NQTOT * NCHUNK * TOPK * 4);

    dim3 gridA(NCHUNK, QGROUPS);
    hipLaunchKernelGGL(score_chunk_topk, gridA, dim3(256), SMEM_A, stream,
                       query, keys, ws_s, ws_i);
    hipLaunchKernelGGL(topk_merge_gather, dim3(NQTOT), dim3(256), 0, stream,
                       ws_s, ws_i, slots, (float*)d_out);
}

// Round 2
// 458.868 us; speedup vs baseline: 2.4561x; 2.4561x over previous
//
#include <hip/hip_runtime.h>

// Problem constants (fixed by setup_inputs).
#define NQ    256       // queries
#define DD    128       // feature dim
#define NK    200000    // stored keys
#define SD    256       // slot dim
#define KTOP  8

#define KSTAGE 80               // keys staged in LDS per iteration
#define KPITCH 272              // bytes per bf16 key row in LDS (256 + 16 pad -> 2-way banks only)
#define STILES (KSTAGE/16)      // 5 MFMA key-tiles per stage
#define NEG_INF (-3.402823466e+38f)

typedef __attribute__((ext_vector_type(8))) short short8;   // 8 bf16 (4 VGPR) MFMA A/B frag
typedef __attribute__((ext_vector_type(4))) float f32x4;    // MFMA C/D frag

// fp32 -> bf16 round-to-nearest-even (no NaN care needed: Gaussian inputs).
__device__ __forceinline__ unsigned short f2bf(float f) {
    unsigned u = __float_as_uint(f);
    u += 0x7fffu + ((u >> 16) & 1u);
    return (unsigned short)(u >> 16);
}

// Min-replace top-T insert; constant indices after unroll.
template <int T>
__device__ __forceinline__ void topk_insert(float (&vs)[T], int (&vi)[T],
                                            float &vmin, float s, int idx) {
    if (s <= vmin) return;
    bool done = false;
#pragma unroll
    for (int j = 0; j < T; ++j)
        if (!done && vs[j] == vmin) { vs[j] = s; vi[j] = idx; done = true; }
    float m = vs[0];
#pragma unroll
    for (int j = 1; j < T; ++j) m = fminf(m, vs[j]);
    vmin = m;
}

// ---------------- Phase A: bf16 MFMA scoring + per-chunk approx top-8 ----------------
// Block: 512 threads = 8 waves; wave w owns q-tile (blockIdx.x*8 + w) = 16 queries.
// A (queries, bf16) lives in 16 VGPR/lane for the whole kernel; keys staged fp32->bf16
// into LDS once per block and consumed by all 8 waves (1 ds_read_b128 per MFMA, A free).
__global__ __launch_bounds__(512, 2)
void score_phaseA(const float* __restrict__ query,
                  const float* __restrict__ keys,
                  float* __restrict__ ws_s,
                  int*   __restrict__ ws_i,
                  int nchunk, int chunkKeys, int nstages) {
    __shared__ __align__(16) char smem[KSTAGE * KPITCH];   // 21760 B

    const int tid  = threadIdx.x;
    const int wave = tid >> 6, lane = tid & 63;
    const int col  = lane & 15, quad = lane >> 4;
    const int qtile = blockIdx.x * 8 + wave;               // 0..15
    const int key0  = blockIdx.y * chunkKeys;

    // --- A fragments: A[m=lane&15][k=quad*8+j], k-chunk c covers k=c*32..c*32+31.
    short8 afrag[4];
    {
        const float* qr = query + (size_t)(qtile * 16 + col) * DD;
#pragma unroll
        for (int c = 0; c < 4; ++c) {
            const float4* p = (const float4*)(qr + c * 32 + quad * 8);
            float4 a = p[0], b = p[1];
            short8 f;
            f[0] = (short)f2bf(a.x); f[1] = (short)f2bf(a.y);
            f[2] = (short)f2bf(a.z); f[3] = (short)f2bf(a.w);
            f[4] = (short)f2bf(b.x); f[5] = (short)f2bf(b.y);
            f[6] = (short)f2bf(b.z); f[7] = (short)f2bf(b.w);
            afrag[c] = f;
        }
    }

    // Per-lane approx top-4 per query (lane sees queries quad*4+r, key col = lane&15).
    float vs[4][4]; int vi[4][4]; float vmin[4];
#pragma unroll
    for (int r = 0; r < 4; ++r) {
        vmin[r] = NEG_INF;
#pragma unroll
        for (int e = 0; e < 4; ++e) { vs[r][e] = NEG_INF; vi[r][e] = -1; }
    }

    // --- staging prologue: stage 0 into registers (5 float4/thread).
    float4 sreg[5];
#pragma unroll
    for (int i = 0; i < 5; ++i) {
        int f = tid + i * 512, r = f >> 5, d4 = f & 31;
        sreg[i] = *(const float4*)(keys + (size_t)(key0 + r) * DD + d4 * 4);
    }

    for (int s = 0; s < nstages; ++s) {
        // write current stage (fp32 regs -> bf16 LDS)
#pragma unroll
        for (int i = 0; i < 5; ++i) {
            int f = tid + i * 512, r = f >> 5, d4 = f & 31;
            ushort4 u;
            u.x = f2bf(sreg[i].x); u.y = f2bf(sreg[i].y);
            u.z = f2bf(sreg[i].z); u.w = f2bf(sreg[i].w);
            *(ushort4*)(smem + r * KPITCH + d4 * 8) = u;
        }
        __syncthreads();
        // prefetch next stage (loads in flight under the MFMA below)
        if (s + 1 < nstages) {
#pragma unroll
            for (int i = 0; i < 5; ++i) {
                int f = tid + i * 512, r = f >> 5, d4 = f & 31;
                sreg[i] = *(const float4*)(keys +
                           (size_t)(key0 + (s + 1) * KSTAGE + r) * DD + d4 * 4);
            }
        }
        const int kb = key0 + s * KSTAGE;
#pragma unroll
        for (int t = 0; t < STILES; ++t) {
            const char* base = smem + (t * 16 + col) * KPITCH + quad * 16;
            short8 b0 = *(const short8*)(base + 0);
            short8 b1 = *(const short8*)(base + 64);
            short8 b2 = *(const short8*)(base + 128);
            short8 b3 = *(const short8*)(base + 192);
            f32x4 acc = {0.f, 0.f, 0.f, 0.f};
            acc = __builtin_amdgcn_mfma_f32_16x16x32_bf16(afrag[0], b0, acc, 0, 0, 0);
            acc = __builtin_amdgcn_mfma_f32_16x16x32_bf16(afrag[1], b1, acc, 0, 0, 0);
            acc = __builtin_amdgcn_mfma_f32_16x16x32_bf16(afrag[2], b2, acc, 0, 0, 0);
            acc = __builtin_amdgcn_mfma_f32_16x16x32_bf16(afrag[3], b3, acc, 0, 0, 0);
            const int kidx = kb + t * 16 + col;
#pragma unroll
            for (int r = 0; r < 4; ++r)
                topk_insert<4>(vs[r], vi[r], vmin[r], acc[r], kidx);
        }
        __syncthreads();
    }

    // --- chunk-end merge: per (query,chunk) top-8 from 16 lanes x top-4.
    // 4 rounds of 2 waves (16 KB dump fits in the 21.76 KB stage buffer).
    float* dump_s = (float*)smem;
    int*   dump_i = (int*)(smem + 8192);
    for (int g = 0; g < 4; ++g) {
        __syncthreads();
        if ((wave >> 1) == g) {
#pragma unroll
            for (int r = 0; r < 4; ++r) {
                int qr = (wave & 1) * 16 + quad * 4 + r;   // 0..31
#pragma unroll
                for (int e = 0; e < 4; ++e) {
                    dump_s[qr * 64 + col * 4 + e] = vs[r][e];
                    dump_i[qr * 64 + col * 4 + e] = vi[r][e];
                }
            }
        }
        __syncthreads();
        if (tid < 32) {
            float ms[KTOP]; int mi[KTOP]; float mm = NEG_INF;
#pragma unroll
            for (int j = 0; j < KTOP; ++j) { ms[j] = NEG_INF; mi[j] = -1; }
            for (int j = 0; j < 64; ++j)
                topk_insert<KTOP>(ms, mi, mm, dump_s[tid * 64 + j], dump_i[tid * 64 + j]);
            const int qg = (blockIdx.x * 8 + 2 * g + (tid >> 4)) * 16 + (tid & 15);
            const size_t base = ((size_t)qg * nchunk + blockIdx.y) * KTOP;
#pragma unroll
            for (int j = 0; j < KTOP; ++j) { ws_s[base + j] = ms[j]; ws_i[base + j] = mi[j]; }
        }
    }
}

// ---------------- Phase B: merge + fp32 rescore + exact top-8 + gather ----------------
__global__ __launch_bounds__(256)
void phaseB(const float* __restrict__ query, const float* __restrict__ keys,
            const float* __restrict__ ws_s, const int* __restrict__ ws_i,
            const float* __restrict__ slots, float* __restrict__ out, int nchunk) {
    const int q = blockIdx.x, t = threadIdx.x;
    const int ncand = nchunk * KTOP;

    __shared__ float ds[256 * KTOP];
    __shared__ int   di[256 * KTOP];
    __shared__ float fs[KTOP]; __shared__ int fi[KTOP];
    __shared__ float thresh;   __shared__ int cnt;
    __shared__ int   clist[128]; __shared__ float cscore[128];

    const float* wsq = ws_s + (size_t)q * ncand;
    const int*   wiq = ws_i + (size_t)q * ncand;

    // 1) approx top-8 (bf16 scores) via local + tree merge.
    float vs[KTOP]; int vi8[KTOP]; float vmin = NEG_INF;
#pragma unroll
    for (int j = 0; j < KTOP; ++j) { vs[j] = NEG_INF; vi8[j] = -1; }
    for (int c = t; c < ncand; c += 256)
        topk_insert<KTOP>(vs, vi8, vmin, wsq[c], wiq[c]);
#pragma unroll
    for (int j = 0; j < KTOP; ++j) { ds[t * KTOP + j] = vs[j]; di[t * KTOP + j] = vi8[j]; }
    __syncthreads();
    for (int step = 128; step >= 1; step >>= 1) {
        if (t < step) {
            for (int j = 0; j < KTOP; ++j)
                topk_insert<KTOP>(vs, vi8, vmin, ds[(t + step) * KTOP + j],
                                  di[(t + step) * KTOP + j]);
#pragma unroll
            for (int j = 0; j < KTOP; ++j) { ds[t * KTOP + j] = vs[j]; di[t * KTOP + j] = vi8[j]; }
        }
        __syncthreads();
    }
    if (t == 0) {
        // bf16 score error << 1.0; margin guarantees every possible true top-8
        // candidate present in ws gets an exact fp32 rescore.
        thresh = vmin - 1.0f;
        cnt = 0;
    }
    __syncthreads();

    // 2) collect candidates above threshold.
    const float th = thresh;
    for (int c = t; c < ncand; c += 256) {
        if (wsq[c] >= th) {
            int p = atomicAdd(&cnt, 1);
            if (p < 128) clist[p] = wiq[c];
        }
    }
    __syncthreads();
    const int m = min(cnt, 128);

    // 3) exact fp32 rescore (2 threads per candidate, 64 dims each).
    {
        const int cand = t >> 1, half = t & 1;
        float sum = 0.f;
        if (cand < m) {
            const float4* kr = (const float4*)(keys + (size_t)clist[cand] * DD + half * 64);
            const float4* qr = (const float4*)(query + (size_t)q * DD + half * 64);
#pragma unroll
            for (int d = 0; d < 16; ++d) {
                float4 a = qr[d], b = kr[d];
                sum = fmaf(a.x, b.x, sum); sum = fmaf(a.y, b.y, sum);
                sum = fmaf(a.z, b.z, sum); sum = fmaf(a.w, b.w, sum);
            }
        }
        float other = __shfl_xor(sum, 1);
        if (cand < m && half == 0) cscore[cand] = sum + other;
    }
    __syncthreads();

    // 4) exact top-8 by (score desc, index asc) — matches lax.top_k ordering.
    if (t == 0) {
#pragma unroll
        for (int j = 0; j < KTOP; ++j) { fs[j] = NEG_INF; fi[j] = 0x7fffffff; }
        for (int c = 0; c < m; ++c) {
            float s = cscore[c]; int id = clist[c];
            int j = KTOP;
            while (j > 0 && (s > fs[j - 1] || (s == fs[j - 1] && id < fi[j - 1]))) --j;
            if (j < KTOP) {
                for (int k = KTOP - 1; k > j; --k) { fs[k] = fs[k - 1]; fi[k] = fi[k - 1]; }
                fs[j] = s; fi[j] = id;
            }
        }
    }
    __syncthreads();

    // 5) gather slots: out = [256][8][256] slots then [256][8] scores.
    const float4* slots4 = (const float4*)slots;
    float4* out4 = (float4*)out;
    const int s4row = SD / 4;   // 64
    for (int f = t; f < KTOP * s4row; f += 256) {
        int j = f >> 6, s4 = f & 63;
        out4[(size_t)q * (KTOP * s4row) + f] = slots4[(size_t)fi[j] * s4row + s4];
    }
    if (t < KTOP)
        out[(size_t)NQ * KTOP * SD + q * KTOP + t] = fs[t];
}

extern "C" void kernel_launch(void* const* d_in, const int* in_sizes, int n_in,
                              void* d_out, int out_size, void* d_ws, size_t ws_size,
                              hipStream_t stream) {
    const float* query = (const float*)d_in[0];
    const float* keys  = (const float*)d_in[1];
    const float* slots = (const float*)d_in[2];
    (void)in_sizes; (void)n_in; (void)out_size;

    // chunk=800 (grid 500) if ws fits 4 MB of candidates, else chunk=1600 (2 MB).
    const int nchunk    = (ws_size >= (size_t)NQ * 250 * KTOP * 8) ? 250 : 125;
    const int chunkKeys = NK / nchunk;
    const int nstages   = chunkKeys / KSTAGE;

    float* ws_s = (float*)d_ws;
    int*   ws_i = (int*)((char*)d_ws + (size_t)NQ * nchunk * KTOP * 4);

    dim3 gridA(2, nchunk);   // x = query-group (fastest): same-chunk pair adjacent for L2 reuse
    hipLaunchKernelGGL(score_phaseA, gridA, dim3(512), 0, stream,
                       query, keys, ws_s, ws_i, nchunk, chunkKeys, nstages);
    hipLaunchKernelGGL(phaseB, dim3(NQ), dim3(256), 0, stream,
                       query, keys, ws_s, ws_i, slots, (float*)d_out, nchunk);
}

// Round 3
// 367.331 us; speedup vs baseline: 3.0681x; 1.2492x over previous
//
#include <hip/hip_runtime.h>

// Problem constants (fixed by setup_inputs).
#define NQ    256       // queries
#define DD    128       // feature dim
#define NK    200000    // stored keys
#define SD    256       // slot dim
#define KTOP  8
#define CAP   1024      // candidate capacity per query (expect ~205)

// Phase A tiling: grid = NCH blocks; block = 256 thr = 4 waves; each block
// scores ALL 256 queries against its CHK-key chunk. Keys hit HBM exactly once.
#define NCH   500
#define CHK   400               // NCH*CHK == NK
#define KST   80                // keys staged in LDS per iteration
#define NST   (CHK/KST)         // 5 stages
#define KT    (KST/16)          // 5 key-tiles per stage
static_assert(NCH * CHK == NK, "chunking must cover keys");

// Workspace byte offsets (total ~1.07 MB).
#define WS_A    0               // bf16 A-fragments: 16 qt x 4 c x 64 lanes x 16B = 64 KB
#define WS_TAUF 65536           // float[256]: tau - margin (phase A filter)
#define WS_TAU  66560           // float[256]: tau (phase B verification)
#define WS_CNT  67584           // int[256]: candidate counts
#define WS_FLAG 68608           // int[256]: fallback flags
#define WS_CAND 69632           // int[256][CAP]: candidate key ids (1 MB)

#define NEG_INF (-3.402823466e+38f)

typedef __attribute__((ext_vector_type(8))) short short8;   // 8 bf16 MFMA A/B frag
typedef __attribute__((ext_vector_type(4))) float f32x4;    // MFMA C/D frag

// fp32 -> bf16 round-to-nearest-even.
__device__ __forceinline__ unsigned f2bf(float f) {
    unsigned u = __float_as_uint(f);
    u += 0x7fffu + ((u >> 16) & 1u);
    return u >> 16;
}

// Exact fp32 dot, two 64-dim halves (same accumulation order as the verified
// R2 rescore -> bitwise-matching scores).
__device__ __forceinline__ float dot128(const float4* __restrict__ qr,
                                        const float4* __restrict__ kr) {
    float s0 = 0.f, s1 = 0.f;
#pragma unroll
    for (int d = 0; d < 16; ++d) {
        float4 a = qr[d], b = kr[d];
        s0 = fmaf(a.x, b.x, s0); s0 = fmaf(a.y, b.y, s0);
        s0 = fmaf(a.z, b.z, s0); s0 = fmaf(a.w, b.w, s0);
    }
#pragma unroll
    for (int d = 16; d < 32; ++d) {
        float4 a = qr[d], b = kr[d];
        s1 = fmaf(a.x, b.x, s1); s1 = fmaf(a.y, b.y, s1);
        s1 = fmaf(a.z, b.z, s1); s1 = fmaf(a.w, b.w, s1);
    }
    return s0 + s1;
}

template <int T>
__device__ __forceinline__ void topk_insert(float (&vs)[T], int (&vi)[T],
                                            float &vmin, float s, int idx) {
    if (s <= vmin) return;
    bool done = false;
#pragma unroll
    for (int j = 0; j < T; ++j)
        if (!done && vs[j] == vmin) { vs[j] = s; vi[j] = idx; done = true; }
    float m = vs[0];
#pragma unroll
    for (int j = 1; j < T; ++j) m = fminf(m, vs[j]);
    vmin = m;
}

// Tree-merge per-thread top-8 lists -> sort -> slot gather -> write. 256 thr.
__device__ void finalize_write(int q, int t, float (&vs)[KTOP], int (&vi)[KTOP],
                               float vmin, float* ds, int* di,
                               const float* __restrict__ slots,
                               float* __restrict__ out) {
#pragma unroll
    for (int j = 0; j < KTOP; ++j) { ds[t * KTOP + j] = vs[j]; di[t * KTOP + j] = vi[j]; }
    __syncthreads();
    for (int step = 128; step >= 1; step >>= 1) {
        if (t < step) {
            for (int j = 0; j < KTOP; ++j)
                topk_insert<KTOP>(vs, vi, vmin, ds[(t + step) * KTOP + j],
                                  di[(t + step) * KTOP + j]);
#pragma unroll
            for (int j = 0; j < KTOP; ++j) { ds[t * KTOP + j] = vs[j]; di[t * KTOP + j] = vi[j]; }
        }
        __syncthreads();
    }
    if (t == 0) {
        // Sort descending, tie-break lower index (matches lax.top_k).
#pragma unroll
        for (int i = 0; i < KTOP; ++i)
#pragma unroll
            for (int j = 0; j < KTOP - 1 - i; ++j) {
                bool swp = (vs[j + 1] > vs[j]) ||
                           (vs[j + 1] == vs[j] && vi[j + 1] < vi[j]);
                if (swp) {
                    float tf = vs[j]; vs[j] = vs[j + 1]; vs[j + 1] = tf;
                    int   ti = vi[j]; vi[j] = vi[j + 1]; vi[j + 1] = ti;
                }
            }
#pragma unroll
        for (int j = 0; j < KTOP; ++j) { ds[j] = vs[j]; di[j] = vi[j]; }
    }
    __syncthreads();
    const float4* slots4 = (const float4*)slots;
    float4* out4 = (float4*)out;
    for (int f = t; f < KTOP * (SD / 4); f += 256) {
        int j = f >> 6, s4 = f & 63;
        out4[(size_t)q * (KTOP * SD / 4) + f] = slots4[(size_t)di[j] * (SD / 4) + s4];
    }
    if (t < KTOP)
        out[(size_t)NQ * KTOP * SD + q * KTOP + t] = ds[t];
}

// ---- prep: query A-fragments (bf16, MFMA layout), tau, counter/flag zeroing ----
__global__ __launch_bounds__(256) void prep(const float* __restrict__ query,
                                            char* __restrict__ ws) {
    __shared__ float qs[16 * DD];
    __shared__ float nrm[16][17];
    const int b = blockIdx.x, t = threadIdx.x;   // b = query-tile 0..15

    const float4* src = (const float4*)(query + (size_t)b * 16 * DD);
    float4* dst = (float4*)qs;
    for (int i = t; i < 512; i += 256) dst[i] = src[i];
    __syncthreads();

    {   // squared-norm partials: row r = t>>4, part p = t&15 (8 elems each)
        int r = t >> 4, p = t & 15;
        float s = 0.f;
#pragma unroll
        for (int j = 0; j < 8; ++j) { float v = qs[r * DD + p * 8 + j]; s = fmaf(v, v, s); }
        nrm[r][p] = s;
    }
    __syncthreads();
    if (t < 16) {
        float s = 0.f;
#pragma unroll
        for (int p = 0; p < 16; ++p) s += nrm[t][p];
        float tau = 3.2f * sqrtf(s);     // scores|q ~ N(0, ||q||^2); E[#>=tau] ~ 137
        ((float*)(ws + WS_TAU))[b * 16 + t]  = tau;
        ((float*)(ws + WS_TAUF))[b * 16 + t] = tau - 1.0f;   // bf16 margin (err <= ~0.35)
    }
    if (b == 0) { ((int*)(ws + WS_CNT))[t] = 0; ((int*)(ws + WS_FLAG))[t] = 0; }

    {   // A-fragment: unit (qt=b, c=t>>6, lane l=t&63) -> 8 bf16 = 16 B
        int c = t >> 6, l = t & 63, col = l & 15, quad = l >> 4;
        const float* row = qs + col * DD + c * 32 + quad * 8;
        int4 pk;
        pk.x = f2bf(row[0]) | (f2bf(row[1]) << 16);
        pk.y = f2bf(row[2]) | (f2bf(row[3]) << 16);
        pk.z = f2bf(row[4]) | (f2bf(row[5]) << 16);
        pk.w = f2bf(row[6]) | (f2bf(row[7]) << 16);
        ((int4*)(ws + WS_A))[(b * 4 + c) * 64 + l] = pk;
    }
}

// ---- phase A: MFMA scoring, threshold filter, candidate append ----
__global__ __launch_bounds__(256, 2)
void phaseA(const float* __restrict__ keys, char* __restrict__ ws) {
    __shared__ __align__(16) char sm[KST * 256];   // 20480 B, fragment-swizzled

    const int tid = threadIdx.x;
    const int w = tid >> 6, lane = tid & 63;
    const int col = lane & 15, quad = lane >> 4;
    const int key0 = blockIdx.x * CHK;

    // A-fragments for 4 query-tiles (queries w*64 .. w*64+63), pinned in VGPRs.
    const short8* wsA = (const short8*)(ws + WS_A);
    short8 A[4][4];
#pragma unroll
    for (int at = 0; at < 4; ++at)
#pragma unroll
        for (int c = 0; c < 4; ++c)
            A[at][c] = wsA[((w * 4 + at) * 4 + c) * 64 + lane];

    // Per-lane filter thresholds for its 16 queries.
    const float* tauf = (const float*)(ws + WS_TAUF);
    float tf[4][4];
#pragma unroll
    for (int at = 0; at < 4; ++at)
#pragma unroll
        for (int r = 0; r < 4; ++r)
            tf[at][r] = tauf[w * 64 + at * 16 + quad * 4 + r];

    int* cnt  = (int*)(ws + WS_CNT);
    int* cand = (int*)(ws + WS_CAND);

    // Staging: thread handles units u = tid + 256*i (i<5); unit -> (tc=u>>6, l=u&63):
    // key row (tc>>2)*16 + (l&15), fp32 elems (tc&3)*32 + (l>>4)*8 .. +8.
    float4 rg[5][2];
#pragma unroll
    for (int i = 0; i < 5; ++i) {
        int u = tid + 256 * i, tc = u >> 6, l = u & 63;
        const float* p = keys + (size_t)(key0 + (tc >> 2) * 16 + (l & 15)) * DD
                              + (tc & 3) * 32 + (l >> 4) * 8;
        rg[i][0] = ((const float4*)p)[0];
        rg[i][1] = ((const float4*)p)[1];
    }

    for (int s = 0; s < NST; ++s) {
        // fp32 regs -> bf16 LDS (lane-contiguous b128 writes, conflict-free)
#pragma unroll
        for (int i = 0; i < 5; ++i) {
            int u = tid + 256 * i;
            int4 pk;
            pk.x = f2bf(rg[i][0].x) | (f2bf(rg[i][0].y) << 16);
            pk.y = f2bf(rg[i][0].z) | (f2bf(rg[i][0].w) << 16);
            pk.z = f2bf(rg[i][1].x) | (f2bf(rg[i][1].y) << 16);
            pk.w = f2bf(rg[i][1].z) | (f2bf(rg[i][1].w) << 16);
            *(int4*)(sm + (size_t)u * 16) = pk;
        }
        __syncthreads();
        if (s + 1 < NST) {   // prefetch next stage under the MFMAs below
#pragma unroll
            for (int i = 0; i < 5; ++i) {
                int u = tid + 256 * i, tc = u >> 6, l = u & 63;
                const float* p = keys + (size_t)(key0 + (s + 1) * KST + (tc >> 2) * 16 + (l & 15)) * DD
                                      + (tc & 3) * 32 + (l >> 4) * 8;
                rg[i][0] = ((const float4*)p)[0];
                rg[i][1] = ((const float4*)p)[1];
            }
        }
        const short8* B = (const short8*)sm;
#pragma unroll
        for (int kt = 0; kt < KT; ++kt) {
            short8 b0 = B[(kt * 4 + 0) * 64 + lane];
            short8 b1 = B[(kt * 4 + 1) * 64 + lane];
            short8 b2 = B[(kt * 4 + 2) * 64 + lane];
            short8 b3 = B[(kt * 4 + 3) * 64 + lane];
            const int kidx = key0 + s * KST + kt * 16 + col;
#pragma unroll
            for (int at = 0; at < 4; ++at) {
                f32x4 acc = {0.f, 0.f, 0.f, 0.f};
                acc = __builtin_amdgcn_mfma_f32_16x16x32_bf16(A[at][0], b0, acc, 0, 0, 0);
                acc = __builtin_amdgcn_mfma_f32_16x16x32_bf16(A[at][1], b1, acc, 0, 0, 0);
                acc = __builtin_amdgcn_mfma_f32_16x16x32_bf16(A[at][2], b2, acc, 0, 0, 0);
                acc = __builtin_amdgcn_mfma_f32_16x16x32_bf16(A[at][3], b3, acc, 0, 0, 0);
#pragma unroll
                for (int r = 0; r < 4; ++r) {
                    if (acc[r] > tf[at][r]) {          // rare (~1e-3 per score)
                        int q = w * 64 + at * 16 + quad * 4 + r;
                        int p = atomicAdd(&cnt[q], 1);
                        if (p < CAP) cand[q * CAP + p] = kidx;
                    }
                }
            }
        }
        __syncthreads();
    }
}

// ---- phase B: exact fp32 rescore of candidates, verify, top-8, gather ----
__global__ __launch_bounds__(256)
void phaseB(const float* __restrict__ query, const float* __restrict__ keys,
            const float* __restrict__ slots, float* __restrict__ out,
            char* __restrict__ ws) {
    const int q = blockIdx.x, t = threadIdx.x;

    __shared__ float cs[CAP];
    __shared__ int   ci[CAP];
    __shared__ int   nAbove;
    __shared__ float ds[256 * KTOP];
    __shared__ int   di[256 * KTOP];

    if (t == 0) nAbove = 0;
    __syncthreads();

    const int m0 = ((const int*)(ws + WS_CNT))[q];
    const int m  = min(m0, CAP);
    const float tq = ((const float*)(ws + WS_TAU))[q];
    const int* cand = (const int*)(ws + WS_CAND) + (size_t)q * CAP;
    const float4* qr = (const float4*)(query + (size_t)q * DD);

    int myAbove = 0;
    for (int c = t; c < m; c += 256) {
        int id = cand[c];
        float s = dot128(qr, (const float4*)(keys + (size_t)id * DD));
        cs[c] = s; ci[c] = id;
        if (s >= tq) ++myAbove;
    }
    if (myAbove) atomicAdd(&nAbove, myAbove);
    __syncthreads();

    // Correctness gate: >=8 exact scores >= tau means every true top-8 key has
    // exact score >= tau, hence bf16 score > tau-1.0, hence is in cand[].
    if (m0 > CAP || nAbove < KTOP) {
        if (t == 0) ((int*)(ws + WS_FLAG))[q] = 1;   // fallback will handle q
        return;
    }

    float vs[KTOP]; int vi[KTOP]; float vmin = NEG_INF;
#pragma unroll
    for (int j = 0; j < KTOP; ++j) { vs[j] = NEG_INF; vi[j] = -1; }
    for (int c = t; c < m; c += 256)
        topk_insert<KTOP>(vs, vi, vmin, cs[c], ci[c]);

    finalize_write(q, t, vs, vi, vmin, ds, di, slots, out);
}

// ---- fallback: exact brute force for flagged queries (never taken in practice) ----
__global__ __launch_bounds__(256)
void fallback(const float* __restrict__ query, const float* __restrict__ keys,
              const float* __restrict__ slots, float* __restrict__ out,
              const char* __restrict__ ws) {
    const int q = blockIdx.x;
    if (((const int*)(ws + WS_FLAG))[q] == 0) return;
    const int t = threadIdx.x;

    __shared__ float ds[256 * KTOP];
    __shared__ int   di[256 * KTOP];

    float vs[KTOP]; int vi[KTOP]; float vmin = NEG_INF;
#pragma unroll
    for (int j = 0; j < KTOP; ++j) { vs[j] = NEG_INF; vi[j] = -1; }

    const float4* qr = (const float4*)(query + (size_t)q * DD);
    for (int id = t; id < NK; id += 256) {
        float s = dot128(qr, (const float4*)(keys + (size_t)id * DD));
        topk_insert<KTOP>(vs, vi, vmin, s, id);
    }
    finalize_write(q, t, vs, vi, vmin, ds, di, slots, out);
}

extern "C" void kernel_launch(void* const* d_in, const int* in_sizes, int n_in,
                              void* d_out, int out_size, void* d_ws, size_t ws_size,
                              hipStream_t stream) {
    const float* query = (const float*)d_in[0];
    const float* keys  = (const float*)d_in[1];
    const float* slots = (const float*)d_in[2];
    (void)in_sizes; (void)n_in; (void)out_size; (void)ws_size;
    char* ws = (char*)d_ws;

    hipLaunchKernelGGL(prep,     dim3(16),  dim3(256), 0, stream, query, ws);
    hipLaunchKernelGGL(phaseA,   dim3(NCH), dim3(256), 0, stream, keys, ws);
    hipLaunchKernelGGL(phaseB,   dim3(NQ),  dim3(256), 0, stream, query, keys, slots,
                       (float*)d_out, ws);
    hipLaunchKernelGGL(fallback, dim3(NQ),  dim3(256), 0, stream, query, keys, slots,
                       (float*)d_out, ws);
}

// Round 4
// 365.160 us; speedup vs baseline: 3.0864x; 1.0059x over previous
//
#include <hip/hip_runtime.h>

// Problem constants (fixed by setup_inputs).
#define NQ    256       // queries
#define DD    128       // feature dim
#define NK    200000    // stored keys
#define SD    256       // slot dim
#define KTOP  8
#define CAP   1024      // candidate capacity per query (expect ~137 above tau)

// Phase A tiling: grid = NCH blocks; block = 256 thr = 4 waves; each block
// scores ALL 256 queries against its CHK-key chunk. Keys hit HBM exactly once.
#define NCH   500
#define CHK   400               // NCH*CHK == NK
#define KST   80                // keys staged in LDS per iteration
#define NST   (CHK/KST)         // 5 stages
#define KT    (KST/16)          // 5 key-tiles per stage
#define BUFB  (KST*256)         // 20480 B per LDS stage buffer
static_assert(NCH * CHK == NK, "chunking must cover keys");

// Workspace byte offsets (total ~1.07 MB; ws is ~819 MB).
#define WS_A    0               // bf16 A-fragments: 16 qt x 4 c x 64 lanes x 16B = 64 KB
#define WS_TAUF 65536           // float[256]: tau - margin (phase A filter)
#define WS_TAU  66560           // float[256]: tau (phase B verification)
#define WS_CNT  67584           // int[256]: candidate counts
#define WS_CAND 69632           // int[256][CAP]: candidate key ids (1 MB)

#define NEG_INF (-3.402823466e+38f)

typedef __attribute__((ext_vector_type(8))) short short8;   // 8 bf16 MFMA A/B frag
typedef __attribute__((ext_vector_type(4))) float f32x4;    // MFMA C/D frag

// fp32 -> bf16 round-to-nearest-even.
__device__ __forceinline__ unsigned f2bf(float f) {
    unsigned u = __float_as_uint(f);
    u += 0x7fffu + ((u >> 16) & 1u);
    return u >> 16;
}

// Exact fp32 dot, two 64-dim halves (verified bitwise vs reference: absmax 0).
__device__ __forceinline__ float dot128(const float4* __restrict__ qr,
                                        const float4* __restrict__ kr) {
    float s0 = 0.f, s1 = 0.f;
#pragma unroll
    for (int d = 0; d < 16; ++d) {
        float4 a = qr[d], b = kr[d];
        s0 = fmaf(a.x, b.x, s0); s0 = fmaf(a.y, b.y, s0);
        s0 = fmaf(a.z, b.z, s0); s0 = fmaf(a.w, b.w, s0);
    }
#pragma unroll
    for (int d = 16; d < 32; ++d) {
        float4 a = qr[d], b = kr[d];
        s1 = fmaf(a.x, b.x, s1); s1 = fmaf(a.y, b.y, s1);
        s1 = fmaf(a.z, b.z, s1); s1 = fmaf(a.w, b.w, s1);
    }
    return s0 + s1;
}

template <int T>
__device__ __forceinline__ void topk_insert(float (&vs)[T], int (&vi)[T],
                                            float &vmin, float s, int idx) {
    if (s <= vmin) return;
    bool done = false;
#pragma unroll
    for (int j = 0; j < T; ++j)
        if (!done && vs[j] == vmin) { vs[j] = s; vi[j] = idx; done = true; }
    float m = vs[0];
#pragma unroll
    for (int j = 1; j < T; ++j) m = fminf(m, vs[j]);
    vmin = m;
}

// Tree-merge per-thread top-8 lists -> sort -> slot gather -> write. 256 thr.
__device__ void finalize_write(int q, int t, float (&vs)[KTOP], int (&vi)[KTOP],
                               float vmin, float* ds, int* di,
                               const float* __restrict__ slots,
                               float* __restrict__ out) {
#pragma unroll
    for (int j = 0; j < KTOP; ++j) { ds[t * KTOP + j] = vs[j]; di[t * KTOP + j] = vi[j]; }
    __syncthreads();
    for (int step = 128; step >= 1; step >>= 1) {
        if (t < step) {
            for (int j = 0; j < KTOP; ++j)
                topk_insert<KTOP>(vs, vi, vmin, ds[(t + step) * KTOP + j],
                                  di[(t + step) * KTOP + j]);
#pragma unroll
            for (int j = 0; j < KTOP; ++j) { ds[t * KTOP + j] = vs[j]; di[t * KTOP + j] = vi[j]; }
        }
        __syncthreads();
    }
    if (t == 0) {
        // Sort descending, tie-break lower index (matches lax.top_k).
#pragma unroll
        for (int i = 0; i < KTOP; ++i)
#pragma unroll
            for (int j = 0; j < KTOP - 1 - i; ++j) {
                bool swp = (vs[j + 1] > vs[j]) ||
                           (vs[j + 1] == vs[j] && vi[j + 1] < vi[j]);
                if (swp) {
                    float tf = vs[j]; vs[j] = vs[j + 1]; vs[j + 1] = tf;
                    int   ti = vi[j]; vi[j] = vi[j + 1]; vi[j + 1] = ti;
                }
            }
#pragma unroll
        for (int j = 0; j < KTOP; ++j) { ds[j] = vs[j]; di[j] = vi[j]; }
    }
    __syncthreads();
    const float4* slots4 = (const float4*)slots;
    float4* out4 = (float4*)out;
    for (int f = t; f < KTOP * (SD / 4); f += 256) {
        int j = f >> 6, s4 = f & 63;
        out4[(size_t)q * (KTOP * SD / 4) + f] = slots4[(size_t)di[j] * (SD / 4) + s4];
    }
    if (t < KTOP)
        out[(size_t)NQ * KTOP * SD + q * KTOP + t] = ds[t];
}

// ---- prep: query A-fragments (bf16, MFMA layout), tau, counter zeroing ----
__global__ __launch_bounds__(256) void prep(const float* __restrict__ query,
                                            char* __restrict__ ws) {
    __shared__ float qs[16 * DD];
    __shared__ float nrm[16][17];
    const int b = blockIdx.x, t = threadIdx.x;   // b = query-tile 0..15

    const float4* src = (const float4*)(query + (size_t)b * 16 * DD);
    float4* dst = (float4*)qs;
    for (int i = t; i < 512; i += 256) dst[i] = src[i];
    __syncthreads();

    {   // squared-norm partials: row r = t>>4, part p = t&15 (8 elems each)
        int r = t >> 4, p = t & 15;
        float s = 0.f;
#pragma unroll
        for (int j = 0; j < 8; ++j) { float v = qs[r * DD + p * 8 + j]; s = fmaf(v, v, s); }
        nrm[r][p] = s;
    }
    __syncthreads();
    if (t < 16) {
        float s = 0.f;
#pragma unroll
        for (int p = 0; p < 16; ++p) s += nrm[t][p];
        float tau = 3.2f * sqrtf(s);     // scores|q ~ N(0, ||q||^2); E[#>=tau] ~ 137
        ((float*)(ws + WS_TAU))[b * 16 + t]  = tau;
        ((float*)(ws + WS_TAUF))[b * 16 + t] = tau - 1.0f;   // bf16-score margin
    }
    if (b == 0) ((int*)(ws + WS_CNT))[t] = 0;

    {   // A-fragment: unit (qt=b, c=t>>6, lane l=t&63) -> 8 bf16 = 16 B
        int c = t >> 6, l = t & 63, col = l & 15, quad = l >> 4;
        const float* row = qs + col * DD + c * 32 + quad * 8;
        int4 pk;
        pk.x = f2bf(row[0]) | (f2bf(row[1]) << 16);
        pk.y = f2bf(row[2]) | (f2bf(row[3]) << 16);
        pk.z = f2bf(row[4]) | (f2bf(row[5]) << 16);
        pk.w = f2bf(row[6]) | (f2bf(row[7]) << 16);
        ((int4*)(ws + WS_A))[(b * 4 + c) * 64 + l] = pk;
    }
}

// ---- phase A: MFMA scoring, threshold filter, candidate append ----
// Double-buffered LDS: one barrier per stage; next stage's load/convert/write
// overlaps current stage's MFMA across the block's 8 waves-in-flight (2 blk/CU).
__global__ __launch_bounds__(256, 2)
void phaseA(const float* __restrict__ keys, char* __restrict__ ws) {
    __shared__ __align__(16) char sm[2 * BUFB];   // 40960 B

    const int tid = threadIdx.x;
    const int w = tid >> 6, lane = tid & 63;
    const int col = lane & 15, quad = lane >> 4;
    const int key0 = blockIdx.x * CHK;

    // A-fragments for 4 query-tiles (queries w*64 .. w*64+63), pinned in VGPRs.
    const short8* wsA = (const short8*)(ws + WS_A);
    short8 A[4][4];
#pragma unroll
    for (int at = 0; at < 4; ++at)
#pragma unroll
        for (int c = 0; c < 4; ++c)
            A[at][c] = wsA[((w * 4 + at) * 4 + c) * 64 + lane];

    // Per-lane filter thresholds for its 16 queries.
    const float* tauf = (const float*)(ws + WS_TAUF);
    float tf[4][4];
#pragma unroll
    for (int at = 0; at < 4; ++at)
#pragma unroll
        for (int r = 0; r < 4; ++r)
            tf[at][r] = tauf[w * 64 + at * 16 + quad * 4 + r];

    int* cnt  = (int*)(ws + WS_CNT);
    int* cand = (int*)(ws + WS_CAND);

    // Staging units: u = tid + 256*i (i<5); (tc=u>>6, l=u&63) ->
    // key row (tc>>2)*16 + (l&15), fp32 elems (tc&3)*32 + (l>>4)*8 .. +8.
    float4 rg[5][2];

#define LOAD_STAGE(S)                                                          \
    {                                                                          \
        _Pragma("unroll")                                                      \
        for (int i = 0; i < 5; ++i) {                                          \
            int u = tid + 256 * i, tc = u >> 6, l = u & 63;                    \
            const float* p = keys +                                            \
                (size_t)(key0 + (S) * KST + (tc >> 2) * 16 + (l & 15)) * DD +  \
                (tc & 3) * 32 + (l >> 4) * 8;                                  \
            rg[i][0] = ((const float4*)p)[0];                                  \
            rg[i][1] = ((const float4*)p)[1];                                  \
        }                                                                      \
    }
#define WRITE_STAGE(BUF)                                                       \
    {                                                                          \
        _Pragma("unroll")                                                      \
        for (int i = 0; i < 5; ++i) {                                          \
            int u = tid + 256 * i;                                             \
            int4 pk;                                                           \
            pk.x = f2bf(rg[i][0].x) | (f2bf(rg[i][0].y) << 16);                \
            pk.y = f2bf(rg[i][0].z) | (f2bf(rg[i][0].w) << 16);                \
            pk.z = f2bf(rg[i][1].x) | (f2bf(rg[i][1].y) << 16);                \
            pk.w = f2bf(rg[i][1].z) | (f2bf(rg[i][1].w) << 16);                \
            *(int4*)(sm + (size_t)(BUF) * BUFB + (size_t)u * 16) = pk;         \
        }                                                                      \
    }

    LOAD_STAGE(0);
    WRITE_STAGE(0);
    __syncthreads();

    for (int s = 0; s < NST; ++s) {
        if (s + 1 < NST) LOAD_STAGE(s + 1);      // loads in flight under MFMAs
        const short8* B = (const short8*)(sm + (s & 1) * BUFB);
#pragma unroll
        for (int kt = 0; kt < KT; ++kt) {
            short8 b0 = B[(kt * 4 + 0) * 64 + lane];
            short8 b1 = B[(kt * 4 + 1) * 64 + lane];
            short8 b2 = B[(kt * 4 + 2) * 64 + lane];
            short8 b3 = B[(kt * 4 + 3) * 64 + lane];
            const int kidx = key0 + s * KST + kt * 16 + col;
#pragma unroll
            for (int at = 0; at < 4; ++at) {
                f32x4 acc = {0.f, 0.f, 0.f, 0.f};
                acc = __builtin_amdgcn_mfma_f32_16x16x32_bf16(A[at][0], b0, acc, 0, 0, 0);
                acc = __builtin_amdgcn_mfma_f32_16x16x32_bf16(A[at][1], b1, acc, 0, 0, 0);
                acc = __builtin_amdgcn_mfma_f32_16x16x32_bf16(A[at][2], b2, acc, 0, 0, 0);
                acc = __builtin_amdgcn_mfma_f32_16x16x32_bf16(A[at][3], b3, acc, 0, 0, 0);
#pragma unroll
                for (int r = 0; r < 4; ++r) {
                    if (acc[r] > tf[at][r]) {          // rare (~7e-4 per score)
                        int q = w * 64 + at * 16 + quad * 4 + r;
                        int p = atomicAdd(&cnt[q], 1);
                        if (p < CAP) cand[q * CAP + p] = kidx;
                    }
                }
            }
        }
        if (s + 1 < NST) {
            WRITE_STAGE((s + 1) & 1);            // other buffer: no read conflict
            __syncthreads();
        }
    }
#undef LOAD_STAGE
#undef WRITE_STAGE
}

// ---- phase B: exact fp32 rescore, verify, top-8, gather (+inline fallback) ----
__global__ __launch_bounds__(256)
void phaseB(const float* __restrict__ query, const float* __restrict__ keys,
            const float* __restrict__ slots, float* __restrict__ out,
            char* __restrict__ ws) {
    const int q = blockIdx.x, t = threadIdx.x;

    __shared__ float cs[CAP];
    __shared__ int   ci[CAP];
    __shared__ int   nAbove;
    __shared__ float ds[256 * KTOP];
    __shared__ int   di[256 * KTOP];

    if (t == 0) nAbove = 0;
    __syncthreads();

    const int m0 = ((const int*)(ws + WS_CNT))[q];
    const int m  = min(m0, CAP);
    const float tq = ((const float*)(ws + WS_TAU))[q];
    const int* cand = (const int*)(ws + WS_CAND) + (size_t)q * CAP;
    const float4* qr = (const float4*)(query + (size_t)q * DD);

    int myAbove = 0;
    for (int c = t; c < m; c += 256) {
        int id = cand[c];
        float s = dot128(qr, (const float4*)(keys + (size_t)id * DD));
        cs[c] = s; ci[c] = id;
        if (s >= tq) ++myAbove;
    }
    if (myAbove) atomicAdd(&nAbove, myAbove);
    __syncthreads();

    float vs[KTOP]; int vi[KTOP]; float vmin = NEG_INF;
#pragma unroll
    for (int j = 0; j < KTOP; ++j) { vs[j] = NEG_INF; vi[j] = -1; }

    // Correctness gate: >=8 exact scores >= tau implies every true top-8 key has
    // exact score >= tau, hence bf16 score > tau-1.0, hence is in cand[].
    // Gate failure (P ~ 0) -> inline exact brute force over all keys.
    if (m0 > CAP || nAbove < KTOP) {
        for (int id = t; id < NK; id += 256) {
            float s = dot128(qr, (const float4*)(keys + (size_t)id * DD));
            topk_insert<KTOP>(vs, vi, vmin, s, id);
        }
    } else {
        for (int c = t; c < m; c += 256)
            topk_insert<KTOP>(vs, vi, vmin, cs[c], ci[c]);
    }

    finalize_write(q, t, vs, vi, vmin, ds, di, slots, out);
}

extern "C" void kernel_launch(void* const* d_in, const int* in_sizes, int n_in,
                              void* d_out, int out_size, void* d_ws, size_t ws_size,
                              hipStream_t stream) {
    const float* query = (const float*)d_in[0];
    const float* keys  = (const float*)d_in[1];
    const float* slots = (const float*)d_in[2];
    (void)in_sizes; (void)n_in; (void)out_size; (void)ws_size;
    char* ws = (char*)d_ws;

    hipLaunchKernelGGL(prep,   dim3(16),  dim3(256), 0, stream, query, ws);
    hipLaunchKernelGGL(phaseA, dim3(NCH), dim3(256), 0, stream, keys, ws);
    hipLaunchKernelGGL(phaseB, dim3(NQ),  dim3(256), 0, stream, query, keys, slots,
                       (float*)d_out, ws);
}